// Round 1
// baseline (663.387 us; speedup 1.0000x reference)
//
#include <hip/hip_runtime.h>
#include <hip/hip_bf16.h>

// Problem constants (match reference)
#define BB 32
#define SS 2048
#define HH 1024
#define CC 5
#define TEMP_INV (1.0f/0.07f)

// ---------------------------------------------------------------------------
// K1: pooling weights — softmax over S of sum(logits[:,:,1:5])
// grid: 64 blocks = (b, which), block: 256. LDS-staged coalesced loads.
__global__ __launch_bounds__(256) void pool_weights(const float* __restrict__ alog,
                             const float* __restrict__ olog,
                             float* __restrict__ w_a,
                             float* __restrict__ w_o) {
    int b = blockIdx.x >> 1;
    int which = blockIdx.x & 1;
    const float* lg = which ? olog : alog;
    float* wout = which ? w_o : w_a;
    __shared__ float raw[SS * CC];   // 40 KB
    __shared__ float sl[SS];         // 8 KB
    __shared__ float red[256];
    int t = threadIdx.x;
    const float4* src = (const float4*)(lg + (size_t)b * SS * CC);
    float4* dst = (float4*)raw;
    for (int i = t; i < SS * CC / 4; i += 256) dst[i] = src[i];
    __syncthreads();
    for (int s = t; s < SS; s += 256) {
        int base = s * 5;
        sl[s] = raw[base + 1] + raw[base + 2] + raw[base + 3] + raw[base + 4];
    }
    __syncthreads();
    float m = -1e30f;
    for (int s = t; s < SS; s += 256) m = fmaxf(m, sl[s]);
    red[t] = m;
    __syncthreads();
    for (int o = 128; o > 0; o >>= 1) {
        if (t < o) red[t] = fmaxf(red[t], red[t + o]);
        __syncthreads();
    }
    m = red[0];
    __syncthreads();
    float sum = 0.f;
    for (int s = t; s < SS; s += 256) {
        float e = expf(sl[s] - m);
        sl[s] = e;
        sum += e;
    }
    red[t] = sum;
    __syncthreads();
    for (int o = 128; o > 0; o >>= 1) {
        if (t < o) red[t] += red[t + o];
        __syncthreads();
    }
    float inv = 1.0f / red[0];
    for (int s = t; s < SS; s += 256) wout[(size_t)b * SS + s] = sl[s] * inv;
}

// ---------------------------------------------------------------------------
// K2: pooling main pass — part[chunk][b][h] = sum over 64 s of span*w
// grid: 1024 = b(32) x chunk(32), block: 256 threads, 4 h each (float4)
// This is the 268 MB streaming kernel — coalesced float4, ~BW-bound.
__global__ __launch_bounds__(256) void pool_partial(const float* __restrict__ span,
                             const float* __restrict__ w_a,
                             const float* __restrict__ w_o,
                             float* __restrict__ part_a,
                             float* __restrict__ part_o) {
    int b = blockIdx.x >> 5;
    int chunk = blockIdx.x & 31;
    int t = threadIdx.x;
    __shared__ float wa[64], wo[64];
    int s0 = chunk * 64;
    if (t < 64) {
        wa[t] = w_a[(size_t)b * SS + s0 + t];
        wo[t] = w_o[(size_t)b * SS + s0 + t];
    }
    __syncthreads();
    const float4* sp = (const float4*)span + ((size_t)b * SS + s0) * (HH / 4) + t;
    float4 aa = {0.f, 0.f, 0.f, 0.f};
    float4 oo = {0.f, 0.f, 0.f, 0.f};
    #pragma unroll 8
    for (int ss = 0; ss < 64; ++ss) {
        float4 v = sp[(size_t)ss * (HH / 4)];
        float fa = wa[ss], fo = wo[ss];
        aa.x += v.x * fa; aa.y += v.y * fa; aa.z += v.z * fa; aa.w += v.w * fa;
        oo.x += v.x * fo; oo.y += v.y * fo; oo.z += v.z * fo; oo.w += v.w * fo;
    }
    size_t idx = ((size_t)chunk * BB + b) * HH + (size_t)t * 4;
    *(float4*)(part_a + idx) = aa;
    *(float4*)(part_o + idx) = oo;
}

// K2r: reduce 32 partials -> a_emb/o_emb [32][1024]
// grid: 256, block: 256  (gid 0..65535; which = hi bit)
__global__ __launch_bounds__(256) void pool_reduce(const float* __restrict__ part_a,
                            const float* __restrict__ part_o,
                            float* __restrict__ a_emb,
                            float* __restrict__ o_emb) {
    int gid = blockIdx.x * 256 + threadIdx.x;
    int which = gid >> 15;
    int r = gid & 32767;
    const float* p = which ? part_o : part_a;
    float s = 0.f;
    #pragma unroll
    for (int c = 0; c < 32; ++c) s += p[(size_t)c * 32768 + r];
    (which ? o_emb : a_emb)[r] = s;
}

// ---------------------------------------------------------------------------
// K3: all three layer-1 GEMMs in one launch, W streamed once, k-split partials.
// Re-tuned vs prev: 128-row k-chunks (2x split), 512-thread blocks (8 waves).
// grid: 384 blocks: [0,64)=a (8j x 8k), [64,128)=o, [128,384)=s (16j x 16k).
// block 512 = 64 j-lanes x 8 b-groups (4 batch rows each).
__global__ __launch_bounds__(512) void gemm1_all(const float* __restrict__ a_emb, const float* __restrict__ o_emb,
                          const float* __restrict__ Wa1, const float* __restrict__ Wo1,
                          const float* __restrict__ Ws1,
                          float* __restrict__ p1_a, float* __restrict__ p1_o,
                          float* __restrict__ p1_s) {
    int bid = blockIdx.x;
    const float* xp; const float* W; float* part; int N, kb, jb;
    if (bid < 64) {
        jb = bid & 7; kb = bid >> 3; N = 512; W = Wa1; part = p1_a;
        xp = a_emb + kb * 128;
    } else if (bid < 128) {
        int r = bid - 64;
        jb = r & 7; kb = r >> 3; N = 512; W = Wo1; part = p1_o;
        xp = o_emb + kb * 128;
    } else {
        int r = bid - 128;
        jb = r & 15; kb = r >> 4; N = 1024; W = Ws1; part = p1_s;
        int kk0 = kb * 128;   // chunks never straddle the 1024 boundary
        xp = (kk0 < 1024) ? (a_emb + kk0) : (o_emb + (kk0 - 1024));
    }
    int k0 = kb * 128;   // global k row offset into W
    __shared__ float xs[32][128];   // 16 KB
    int t = threadIdx.x;
    #pragma unroll
    for (int i = 0; i < 2; ++i) {
        int f = t + i * 512;        // float4 index into [32][32]
        int b = f >> 5;
        int kk = (f & 31) * 4;
        *(float4*)(&xs[b][kk]) = *(const float4*)(xp + (size_t)b * HH + kk);
    }
    __syncthreads();
    int jl = t & 63, bg = t >> 6;   // bg 0..7
    int j = jb * 64 + jl;
    float acc[4] = {0.f, 0.f, 0.f, 0.f};
    const float* Wp = W + (size_t)k0 * N + j;
    for (int k = 0; k < 128; k += 4) {
        float w0 = Wp[(size_t)(k + 0) * N];
        float w1 = Wp[(size_t)(k + 1) * N];
        float w2 = Wp[(size_t)(k + 2) * N];
        float w3 = Wp[(size_t)(k + 3) * N];
        #pragma unroll
        for (int bi = 0; bi < 4; ++bi) {
            float4 xv = *(const float4*)(&xs[bg * 4 + bi][k]);
            acc[bi] += xv.x * w0 + xv.y * w1 + xv.z * w2 + xv.w * w3;
        }
    }
    float* pp = part + (size_t)kb * 32 * N + j;
    #pragma unroll
    for (int bi = 0; bi < 4; ++bi)
        pp[(size_t)(bg * 4 + bi) * N] = acc[bi];
}

// ---------------------------------------------------------------------------
// K4: layer 2 for a/o/s, with fused k-split reduction + bias + relu of layer1.
// Re-tuned vs prev: 512 threads, GEMV k-split across thread groups (chain
// 1024->512 / 512->128), all lanes active in a/o branch.
// grid: 96 blocks: [0,32)=a, [32,64)=o, [64,96)=s. block: 512.
__global__ __launch_bounds__(512) void layer2_all(const float* __restrict__ p1_a, const float* __restrict__ ba1,
                           const float* __restrict__ Wa2, const float* __restrict__ ba2,
                           const float* __restrict__ p1_o, const float* __restrict__ bo1,
                           const float* __restrict__ Wo2, const float* __restrict__ bo2,
                           const float* __restrict__ p1_s, const float* __restrict__ bs1,
                           const float* __restrict__ Ws2, const float* __restrict__ bs2,
                           float* __restrict__ a_proj, float* __restrict__ o_proj,
                           float* __restrict__ s_proj) {
    __shared__ float x[1024];
    __shared__ float red[512];
    int bid = blockIdx.x;
    int t = threadIdx.x;
    if (bid < 64) {
        int which = bid >> 5;
        int b = bid & 31;
        const float* part = which ? p1_o : p1_a;
        const float* b1 = which ? bo1 : ba1;
        const float* W2 = which ? Wo2 : Wa2;
        const float* b2 = which ? bo2 : ba2;
        float* out = (which ? o_proj : a_proj) + (size_t)b * 128;
        {   // reduce 8 k-split partials + bias + relu  (t = j, one per thread)
            float s = b1[t];
            #pragma unroll
            for (int kb = 0; kb < 8; ++kb) s += part[(size_t)kb * 32 * 512 + (size_t)b * 512 + t];
            x[t] = fmaxf(s, 0.f);
        }
        __syncthreads();
        int jj = t & 127, kh = t >> 7;     // 4-way k split
        float acc = (kh == 0) ? b2[jj] : 0.f;
        const float* Wc = W2 + jj;
        for (int k = kh * 128; k < kh * 128 + 128; ++k) acc += x[k] * Wc[(size_t)k * 128];
        red[t] = acc;
        __syncthreads();
        float tot = 0.f;
        if (t < 128) tot = red[t] + red[t + 128] + red[t + 256] + red[t + 384];
        __syncthreads();
        if (t < 128) red[t] = tot * tot;
        __syncthreads();
        for (int o = 64; o > 0; o >>= 1) {
            if (t < o) red[t] += red[t + o];
            __syncthreads();
        }
        float n = fmaxf(sqrtf(red[0]), 1e-12f);
        if (t < 128) out[t] = tot / n;
    } else {
        int b = bid - 64;
        for (int j = t; j < 1024; j += 512) {
            float s = bs1[j];
            #pragma unroll
            for (int kb = 0; kb < 16; ++kb) s += p1_s[(size_t)kb * 32 * 1024 + (size_t)b * 1024 + j];
            x[j] = fmaxf(s, 0.f);
        }
        __syncthreads();
        int jj = t & 255, kh = t >> 8;     // 2-way k split
        float acc = (kh == 0) ? bs2[jj] : 0.f;
        const float* Wc = Ws2 + jj;
        for (int k = kh * 512; k < kh * 512 + 512; ++k) acc += x[k] * Wc[(size_t)k * 256];
        red[t] = acc;
        __syncthreads();
        float tot = 0.f;
        if (t < 256) tot = red[t] + red[t + 256];
        __syncthreads();
        if (t < 256) red[t] = tot * tot;
        __syncthreads();
        for (int o = 128; o > 0; o >>= 1) {
            if (t < o) red[t] += red[t + o];
            __syncthreads();
        }
        float n = fmaxf(sqrtf(red[0]), 1e-12f);
        if (t < 256) s_proj[(size_t)b * 256 + t] = tot / n;
    }
}

// ---------------------------------------------------------------------------
// K5: losses. One block, 1024 threads: thread (i,j) = one 32x32 sim entry.
// LDS rows padded to 129/257 floats: op[j][k] / sp[j][k] reads across the 32
// j-lanes were (j*128+k)%32 == k%32 -> 32-way bank conflict; padding makes
// them (j+k)%32 -> conflict-free.
__global__ __launch_bounds__(1024) void loss_kernel(const float* __restrict__ a_proj,
                            const float* __restrict__ o_proj,
                            const float* __restrict__ s_proj,
                            const int* __restrict__ labels,
                            float* __restrict__ out) {
    __shared__ float ap[BB][129];
    __shared__ float op[BB][129];
    __shared__ float sp[BB][257];
    __shared__ float rowv[BB], rownt[BB];
    __shared__ int hp[BB], lab[BB];
    int t = threadIdx.x;
    for (int idx = t; idx < BB * 128; idx += 1024) {
        int r = idx >> 7, c = idx & 127;
        ap[r][c] = a_proj[idx];
        op[r][c] = o_proj[idx];
    }
    for (int idx = t; idx < BB * 256; idx += 1024) {
        int r = idx >> 8, c = idx & 255;
        sp[r][c] = s_proj[idx];
    }
    if (t < BB) lab[t] = labels[t];
    __syncthreads();
    int i = t >> 5, j = t & 31;

    // re-normalize sp rows (reference calls _l2norm again inside _ntxent)
    float ssq = 0.f;
    #pragma unroll
    for (int k = 0; k < 8; ++k) {
        float v = sp[i][j * 8 + k];
        ssq += v * v;
    }
    for (int m = 16; m > 0; m >>= 1) ssq += __shfl_xor(ssq, m, 64);
    float inv = 1.0f / fmaxf(sqrtf(ssq), 1e-12f);
    for (int k = j; k < 256; k += 32) sp[i][k] *= inv;
    __syncthreads();

    // infonce: sim = a_proj @ o_proj.T / TEMP
    float dot = 0.f;
    for (int k = 0; k < 128; ++k) dot += ap[i][k] * op[j][k];
    float e = expf(dot * TEMP_INV);
    float maskv = (i == j) ? 1.0f : ((lab[i] == lab[j]) ? 0.5f : 0.0f);
    float num = e * maskv, den = e;
    for (int m = 16; m > 0; m >>= 1) {
        num += __shfl_xor(num, m, 64);
        den += __shfl_xor(den, m, 64);
    }

    // ntxent
    float dn = 0.f;
    for (int k = 0; k < 256; ++k) dn += sp[i][k] * sp[j][k];
    float en = expf(dn * TEMP_INV);
    float mnt = (lab[i] == lab[j]) ? ((i == j) ? 0.f : 1.f) : 0.f;
    float pos = en * mnt, neg = en * (1.f - mnt), pc = mnt;
    for (int m = 16; m > 0; m >>= 1) {
        pos += __shfl_xor(pos, m, 64);
        neg += __shfl_xor(neg, m, 64);
        pc += __shfl_xor(pc, m, 64);
    }

    if (j == 0) {
        rowv[i] = -logf(num / den + 1e-8f);
        bool has = pc > 0.f;
        rownt[i] = has ? (-logf(pos / (pos + neg) + 1e-8f) / fmaxf(pc, 1.0f)) : 0.f;
        hp[i] = has ? 1 : 0;
    }
    __syncthreads();
    if (t == 0) {
        float inf = 0.f, nt = 0.f;
        int h = 0;
        for (int q = 0; q < BB; ++q) { inf += rowv[q]; nt += rownt[q]; h += hp[q]; }
        inf /= (float)BB;
        nt /= (float)(h > 0 ? h : 1);
        out[0] = 1.0f * inf + 0.5f * nt;
    }
}

// ---------------------------------------------------------------------------
extern "C" void kernel_launch(void* const* d_in, const int* in_sizes, int n_in,
                              void* d_out, int out_size, void* d_ws, size_t ws_size,
                              hipStream_t stream) {
    const float* span  = (const float*)d_in[0];
    const float* alog  = (const float*)d_in[1];
    const float* olog  = (const float*)d_in[2];
    const int*   labs  = (const int*)d_in[3];
    const float* Wa1   = (const float*)d_in[4];
    const float* ba1   = (const float*)d_in[5];
    const float* Wa2   = (const float*)d_in[6];
    const float* ba2   = (const float*)d_in[7];
    const float* Wo1   = (const float*)d_in[8];
    const float* bo1   = (const float*)d_in[9];
    const float* Wo2   = (const float*)d_in[10];
    const float* bo2   = (const float*)d_in[11];
    const float* Ws1   = (const float*)d_in[12];
    const float* bs1   = (const float*)d_in[13];
    const float* Ws2   = (const float*)d_in[14];
    const float* bs2   = (const float*)d_in[15];

    float* ws = (float*)d_ws;
    float* w_a    = ws;                  // 65536
    float* w_o    = ws + 65536;          // 65536
    float* part_a = ws + 131072;         // 32*32768 = 1048576
    float* part_o = ws + 1179648;        // 1048576
    float* a_emb  = ws + 2228224;        // 32768
    float* o_emb  = ws + 2260992;        // 32768
    float* p1_a   = ws + 2293760;        // 8*32*512 = 131072
    float* p1_o   = ws + 2424832;        // 131072
    float* p1_s   = ws + 2555904;        // 16*32*1024 = 524288
    float* a_proj = ws + 3080192;        // 4096
    float* o_proj = ws + 3084288;        // 4096
    float* s_proj = ws + 3088384;        // 8192

    hipLaunchKernelGGL(pool_weights, dim3(64), dim3(256), 0, stream, alog, olog, w_a, w_o);
    hipLaunchKernelGGL(pool_partial, dim3(1024), dim3(256), 0, stream,
                       span, w_a, w_o, part_a, part_o);
    hipLaunchKernelGGL(pool_reduce, dim3(256), dim3(256), 0, stream,
                       part_a, part_o, a_emb, o_emb);
    hipLaunchKernelGGL(gemm1_all, dim3(384), dim3(512), 0, stream,
                       a_emb, o_emb, Wa1, Wo1, Ws1, p1_a, p1_o, p1_s);
    hipLaunchKernelGGL(layer2_all, dim3(96), dim3(512), 0, stream,
                       p1_a, ba1, Wa2, ba2, p1_o, bo1, Wo2, bo2,
                       p1_s, bs1, Ws2, bs2, a_proj, o_proj, s_proj);
    hipLaunchKernelGGL(loss_kernel, dim3(1), dim3(1024), 0, stream,
                       a_proj, o_proj, s_proj, labs, (float*)d_out);
}

// Round 2
// 456.095 us; speedup vs baseline: 1.4545x; 1.4545x over previous
//
#include <hip/hip_runtime.h>
#include <hip/hip_bf16.h>

// Problem constants (match reference)
#define BB 32
#define SS 2048
#define HH 1024
#define CC 5
#define TEMP_INV (1.0f/0.07f)

// ---------------------------------------------------------------------------
// K1: pooling weights — softmax over S of sum(logits[:,:,1:5])
// grid: 64 blocks = (b, which), block: 256. LDS-staged coalesced loads.
__global__ __launch_bounds__(256) void pool_weights(const float* __restrict__ alog,
                             const float* __restrict__ olog,
                             float* __restrict__ w_a,
                             float* __restrict__ w_o) {
    int b = blockIdx.x >> 1;
    int which = blockIdx.x & 1;
    const float* lg = which ? olog : alog;
    float* wout = which ? w_o : w_a;
    __shared__ float raw[SS * CC];   // 40 KB
    __shared__ float sl[SS];         // 8 KB
    __shared__ float red[256];
    int t = threadIdx.x;
    const float4* src = (const float4*)(lg + (size_t)b * SS * CC);
    float4* dst = (float4*)raw;
    #pragma unroll 4
    for (int i = t; i < SS * CC / 4; i += 256) dst[i] = src[i];
    __syncthreads();
    for (int s = t; s < SS; s += 256) {
        int base = s * 5;
        sl[s] = raw[base + 1] + raw[base + 2] + raw[base + 3] + raw[base + 4];
    }
    __syncthreads();
    float m = -1e30f;
    for (int s = t; s < SS; s += 256) m = fmaxf(m, sl[s]);
    red[t] = m;
    __syncthreads();
    for (int o = 128; o > 0; o >>= 1) {
        if (t < o) red[t] = fmaxf(red[t], red[t + o]);
        __syncthreads();
    }
    m = red[0];
    __syncthreads();
    float sum = 0.f;
    for (int s = t; s < SS; s += 256) {
        float e = expf(sl[s] - m);
        sl[s] = e;
        sum += e;
    }
    red[t] = sum;
    __syncthreads();
    for (int o = 128; o > 0; o >>= 1) {
        if (t < o) red[t] += red[t + o];
        __syncthreads();
    }
    float inv = 1.0f / red[0];
    for (int s = t; s < SS; s += 256) wout[(size_t)b * SS + s] = sl[s] * inv;
}

// ---------------------------------------------------------------------------
// K2: pooling main pass — part[chunk][b][h] = sum over 64 s of span*w
// grid: 1024 = b(32) x chunk(32), block: 256 threads, 4 h each (float4)
// This is the 268 MB streaming kernel — at its data roofline (~43 us min).
__global__ __launch_bounds__(256) void pool_partial(const float* __restrict__ span,
                             const float* __restrict__ w_a,
                             const float* __restrict__ w_o,
                             float* __restrict__ part_a,
                             float* __restrict__ part_o) {
    int b = blockIdx.x >> 5;
    int chunk = blockIdx.x & 31;
    int t = threadIdx.x;
    __shared__ float wa[64], wo[64];
    int s0 = chunk * 64;
    if (t < 64) {
        wa[t] = w_a[(size_t)b * SS + s0 + t];
        wo[t] = w_o[(size_t)b * SS + s0 + t];
    }
    __syncthreads();
    const float4* sp = (const float4*)span + ((size_t)b * SS + s0) * (HH / 4) + t;
    float4 aa = {0.f, 0.f, 0.f, 0.f};
    float4 oo = {0.f, 0.f, 0.f, 0.f};
    #pragma unroll 8
    for (int ss = 0; ss < 64; ++ss) {
        float4 v = sp[(size_t)ss * (HH / 4)];
        float fa = wa[ss], fo = wo[ss];
        aa.x += v.x * fa; aa.y += v.y * fa; aa.z += v.z * fa; aa.w += v.w * fa;
        oo.x += v.x * fo; oo.y += v.y * fo; oo.z += v.z * fo; oo.w += v.w * fo;
    }
    size_t idx = ((size_t)chunk * BB + b) * HH + (size_t)t * 4;
    *(float4*)(part_a + idx) = aa;
    *(float4*)(part_o + idx) = oo;
}

// K2r: reduce 32 partials -> a_emb/o_emb [32][1024]
__global__ __launch_bounds__(256) void pool_reduce(const float* __restrict__ part_a,
                            const float* __restrict__ part_o,
                            float* __restrict__ a_emb,
                            float* __restrict__ o_emb) {
    int gid = blockIdx.x * 256 + threadIdx.x;
    int which = gid >> 15;
    int r = gid & 32767;
    const float* p = which ? part_o : part_a;
    float s = 0.f;
    #pragma unroll
    for (int c = 0; c < 32; ++c) s += p[(size_t)c * 32768 + r];
    (which ? o_emb : a_emb)[r] = s;
}

// ---------------------------------------------------------------------------
// K3: all three layer-1 GEMMs in one launch, W streamed once, k-split partials.
// grid: 384 blocks: [0,64)=a (8j x 8k), [64,128)=o, [128,384)=s (16j x 16k).
// block 512 = 64 j-lanes x 8 b-groups (4 batch rows each).
// unroll 4 on the k+=4 loop -> 16 scalar W loads in flight (latency chain fix).
__global__ __launch_bounds__(512) void gemm1_all(const float* __restrict__ a_emb, const float* __restrict__ o_emb,
                          const float* __restrict__ Wa1, const float* __restrict__ Wo1,
                          const float* __restrict__ Ws1,
                          float* __restrict__ p1_a, float* __restrict__ p1_o,
                          float* __restrict__ p1_s) {
    int bid = blockIdx.x;
    const float* xp; const float* W; float* part; int N, kb, jb;
    if (bid < 64) {
        jb = bid & 7; kb = bid >> 3; N = 512; W = Wa1; part = p1_a;
        xp = a_emb + kb * 128;
    } else if (bid < 128) {
        int r = bid - 64;
        jb = r & 7; kb = r >> 3; N = 512; W = Wo1; part = p1_o;
        xp = o_emb + kb * 128;
    } else {
        int r = bid - 128;
        jb = r & 15; kb = r >> 4; N = 1024; W = Ws1; part = p1_s;
        int kk0 = kb * 128;   // chunks never straddle the 1024 boundary
        xp = (kk0 < 1024) ? (a_emb + kk0) : (o_emb + (kk0 - 1024));
    }
    int k0 = kb * 128;   // global k row offset into W
    __shared__ float xs[32][128];   // 16 KB
    int t = threadIdx.x;
    #pragma unroll
    for (int i = 0; i < 2; ++i) {
        int f = t + i * 512;        // float4 index into [32][32]
        int b = f >> 5;
        int kk = (f & 31) * 4;
        *(float4*)(&xs[b][kk]) = *(const float4*)(xp + (size_t)b * HH + kk);
    }
    __syncthreads();
    int jl = t & 63, bg = t >> 6;   // bg 0..7
    int j = jb * 64 + jl;
    float acc[4] = {0.f, 0.f, 0.f, 0.f};
    const float* Wp = W + (size_t)k0 * N + j;
    #pragma unroll 4
    for (int k = 0; k < 128; k += 4) {
        float w0 = Wp[(size_t)(k + 0) * N];
        float w1 = Wp[(size_t)(k + 1) * N];
        float w2 = Wp[(size_t)(k + 2) * N];
        float w3 = Wp[(size_t)(k + 3) * N];
        #pragma unroll
        for (int bi = 0; bi < 4; ++bi) {
            float4 xv = *(const float4*)(&xs[bg * 4 + bi][k]);
            acc[bi] += xv.x * w0 + xv.y * w1 + xv.z * w2 + xv.w * w3;
        }
    }
    float* pp = part + (size_t)kb * 32 * N + j;
    #pragma unroll
    for (int bi = 0; bi < 4; ++bi)
        pp[(size_t)(bg * 4 + bi) * N] = acc[bi];
}

// ---------------------------------------------------------------------------
// K4: layer 2 for a/o/s, fused k-split reduction + bias + relu of layer1.
// ROUND-2 FIX: the GEMV k-loops were un-unrolled -> one full memory latency
// per iteration (rocprof: 187us, VALUBusy 0.87%). #pragma unroll 16 puts 16
// independent W2 loads in flight; chain drops from 512*~400cy to 32*~250cy.
// grid: 96 blocks: [0,32)=a, [32,64)=o, [64,96)=s. block: 512.
__global__ __launch_bounds__(512) void layer2_all(const float* __restrict__ p1_a, const float* __restrict__ ba1,
                           const float* __restrict__ Wa2, const float* __restrict__ ba2,
                           const float* __restrict__ p1_o, const float* __restrict__ bo1,
                           const float* __restrict__ Wo2, const float* __restrict__ bo2,
                           const float* __restrict__ p1_s, const float* __restrict__ bs1,
                           const float* __restrict__ Ws2, const float* __restrict__ bs2,
                           float* __restrict__ a_proj, float* __restrict__ o_proj,
                           float* __restrict__ s_proj) {
    __shared__ float x[1024];
    __shared__ float red[512];
    int bid = blockIdx.x;
    int t = threadIdx.x;
    if (bid < 64) {
        int which = bid >> 5;
        int b = bid & 31;
        const float* part = which ? p1_o : p1_a;
        const float* b1 = which ? bo1 : ba1;
        const float* W2 = which ? Wo2 : Wa2;
        const float* b2 = which ? bo2 : ba2;
        float* out = (which ? o_proj : a_proj) + (size_t)b * 128;
        {   // reduce 8 k-split partials + bias + relu  (t = j, one per thread)
            float s = b1[t];
            #pragma unroll
            for (int kb = 0; kb < 8; ++kb) s += part[(size_t)kb * 32 * 512 + (size_t)b * 512 + t];
            x[t] = fmaxf(s, 0.f);
        }
        __syncthreads();
        int jj = t & 127, kh = t >> 7;     // 4-way k split
        int kbase = kh * 128;
        const float* Wc = W2 + (size_t)kbase * 128 + jj;
        float acc = 0.f;
        #pragma unroll 16
        for (int kk = 0; kk < 128; ++kk)
            acc += x[kbase + kk] * Wc[(size_t)kk * 128];
        if (kh == 0) acc += b2[jj];
        red[t] = acc;
        __syncthreads();
        float tot = 0.f;
        if (t < 128) tot = red[t] + red[t + 128] + red[t + 256] + red[t + 384];
        __syncthreads();
        if (t < 128) red[t] = tot * tot;
        __syncthreads();
        for (int o = 64; o > 0; o >>= 1) {
            if (t < o) red[t] += red[t + o];
            __syncthreads();
        }
        float n = fmaxf(sqrtf(red[0]), 1e-12f);
        if (t < 128) out[t] = tot / n;
    } else {
        int b = bid - 64;
        for (int j = t; j < 1024; j += 512) {
            float s = bs1[j];
            #pragma unroll
            for (int kb = 0; kb < 16; ++kb) s += p1_s[(size_t)kb * 32 * 1024 + (size_t)b * 1024 + j];
            x[j] = fmaxf(s, 0.f);
        }
        __syncthreads();
        int jj = t & 255, kh = t >> 8;     // 2-way k split
        int kbase = kh * 512;
        const float* Wc = Ws2 + (size_t)kbase * 256 + jj;
        float acc = 0.f;
        #pragma unroll 16
        for (int kk = 0; kk < 512; ++kk)
            acc += x[kbase + kk] * Wc[(size_t)kk * 256];
        if (kh == 0) acc += bs2[jj];
        red[t] = acc;
        __syncthreads();
        float tot = 0.f;
        if (t < 256) tot = red[t] + red[t + 256];
        __syncthreads();
        if (t < 256) red[t] = tot * tot;
        __syncthreads();
        for (int o = 128; o > 0; o >>= 1) {
            if (t < o) red[t] += red[t + o];
            __syncthreads();
        }
        float n = fmaxf(sqrtf(red[0]), 1e-12f);
        if (t < 256) s_proj[(size_t)b * 256 + t] = tot / n;
    }
}

// ---------------------------------------------------------------------------
// K5: losses. One block, 1024 threads: thread (i,j) = one 32x32 sim entry.
// LDS rows padded to 129/257 floats (conflict-free); dot loops unrolled so
// LDS reads pipeline.
__global__ __launch_bounds__(1024) void loss_kernel(const float* __restrict__ a_proj,
                            const float* __restrict__ o_proj,
                            const float* __restrict__ s_proj,
                            const int* __restrict__ labels,
                            float* __restrict__ out) {
    __shared__ float ap[BB][129];
    __shared__ float op[BB][129];
    __shared__ float sp[BB][257];
    __shared__ float rowv[BB], rownt[BB];
    __shared__ int hp[BB], lab[BB];
    int t = threadIdx.x;
    for (int idx = t; idx < BB * 128; idx += 1024) {
        int r = idx >> 7, c = idx & 127;
        ap[r][c] = a_proj[idx];
        op[r][c] = o_proj[idx];
    }
    for (int idx = t; idx < BB * 256; idx += 1024) {
        int r = idx >> 8, c = idx & 255;
        sp[r][c] = s_proj[idx];
    }
    if (t < BB) lab[t] = labels[t];
    __syncthreads();
    int i = t >> 5, j = t & 31;

    // re-normalize sp rows (reference calls _l2norm again inside _ntxent)
    float ssq = 0.f;
    #pragma unroll
    for (int k = 0; k < 8; ++k) {
        float v = sp[i][j * 8 + k];
        ssq += v * v;
    }
    for (int m = 16; m > 0; m >>= 1) ssq += __shfl_xor(ssq, m, 64);
    float inv = 1.0f / fmaxf(sqrtf(ssq), 1e-12f);
    for (int k = j; k < 256; k += 32) sp[i][k] *= inv;
    __syncthreads();

    // infonce: sim = a_proj @ o_proj.T / TEMP
    float dot = 0.f;
    #pragma unroll 16
    for (int k = 0; k < 128; ++k) dot += ap[i][k] * op[j][k];
    float e = expf(dot * TEMP_INV);
    float maskv = (i == j) ? 1.0f : ((lab[i] == lab[j]) ? 0.5f : 0.0f);
    float num = e * maskv, den = e;
    for (int m = 16; m > 0; m >>= 1) {
        num += __shfl_xor(num, m, 64);
        den += __shfl_xor(den, m, 64);
    }

    // ntxent
    float dn = 0.f;
    #pragma unroll 16
    for (int k = 0; k < 256; ++k) dn += sp[i][k] * sp[j][k];
    float en = expf(dn * TEMP_INV);
    float mnt = (lab[i] == lab[j]) ? ((i == j) ? 0.f : 1.f) : 0.f;
    float pos = en * mnt, neg = en * (1.f - mnt), pc = mnt;
    for (int m = 16; m > 0; m >>= 1) {
        pos += __shfl_xor(pos, m, 64);
        neg += __shfl_xor(neg, m, 64);
        pc += __shfl_xor(pc, m, 64);
    }

    if (j == 0) {
        rowv[i] = -logf(num / den + 1e-8f);
        bool has = pc > 0.f;
        rownt[i] = has ? (-logf(pos / (pos + neg) + 1e-8f) / fmaxf(pc, 1.0f)) : 0.f;
        hp[i] = has ? 1 : 0;
    }
    __syncthreads();
    if (t == 0) {
        float inf = 0.f, nt = 0.f;
        int h = 0;
        for (int q = 0; q < BB; ++q) { inf += rowv[q]; nt += rownt[q]; h += hp[q]; }
        inf /= (float)BB;
        nt /= (float)(h > 0 ? h : 1);
        out[0] = 1.0f * inf + 0.5f * nt;
    }
}

// ---------------------------------------------------------------------------
extern "C" void kernel_launch(void* const* d_in, const int* in_sizes, int n_in,
                              void* d_out, int out_size, void* d_ws, size_t ws_size,
                              hipStream_t stream) {
    const float* span  = (const float*)d_in[0];
    const float* alog  = (const float*)d_in[1];
    const float* olog  = (const float*)d_in[2];
    const int*   labs  = (const int*)d_in[3];
    const float* Wa1   = (const float*)d_in[4];
    const float* ba1   = (const float*)d_in[5];
    const float* Wa2   = (const float*)d_in[6];
    const float* ba2   = (const float*)d_in[7];
    const float* Wo1   = (const float*)d_in[8];
    const float* bo1   = (const float*)d_in[9];
    const float* Wo2   = (const float*)d_in[10];
    const float* bo2   = (const float*)d_in[11];
    const float* Ws1   = (const float*)d_in[12];
    const float* bs1   = (const float*)d_in[13];
    const float* Ws2   = (const float*)d_in[14];
    const float* bs2   = (const float*)d_in[15];

    float* ws = (float*)d_ws;
    float* w_a    = ws;                  // 65536
    float* w_o    = ws + 65536;          // 65536
    float* part_a = ws + 131072;         // 32*32768 = 1048576
    float* part_o = ws + 1179648;        // 1048576
    float* a_emb  = ws + 2228224;        // 32768
    float* o_emb  = ws + 2260992;        // 32768
    float* p1_a   = ws + 2293760;        // 8*32*512 = 131072
    float* p1_o   = ws + 2424832;        // 131072
    float* p1_s   = ws + 2555904;        // 16*32*1024 = 524288
    float* a_proj = ws + 3080192;        // 4096
    float* o_proj = ws + 3084288;        // 4096
    float* s_proj = ws + 3088384;        // 8192

    hipLaunchKernelGGL(pool_weights, dim3(64), dim3(256), 0, stream, alog, olog, w_a, w_o);
    hipLaunchKernelGGL(pool_partial, dim3(1024), dim3(256), 0, stream,
                       span, w_a, w_o, part_a, part_o);
    hipLaunchKernelGGL(pool_reduce, dim3(256), dim3(256), 0, stream,
                       part_a, part_o, a_emb, o_emb);
    hipLaunchKernelGGL(gemm1_all, dim3(384), dim3(512), 0, stream,
                       a_emb, o_emb, Wa1, Wo1, Ws1, p1_a, p1_o, p1_s);
    hipLaunchKernelGGL(layer2_all, dim3(96), dim3(512), 0, stream,
                       p1_a, ba1, Wa2, ba2, p1_o, bo1, Wo2, bo2,
                       p1_s, bs1, Ws2, bs2, a_proj, o_proj, s_proj);
    hipLaunchKernelGGL(loss_kernel, dim3(1), dim3(1024), 0, stream,
                       a_proj, o_proj, s_proj, labs, (float*)d_out);
}

// Round 3
// 447.720 us; speedup vs baseline: 1.4817x; 1.0187x over previous
//
#include <hip/hip_runtime.h>
#include <hip/hip_bf16.h>

// Problem constants (match reference)
#define BB 32
#define SS 2048
#define HH 1024
#define CC 5
#define TEMP_INV (1.0f/0.07f)

// ---------------------------------------------------------------------------
// K1: pooling weights — softmax over S of sum(logits[:,:,1:5])
// grid: 64 blocks = (b, which), block: 256. LDS-staged coalesced loads.
__global__ __launch_bounds__(256) void pool_weights(const float* __restrict__ alog,
                             const float* __restrict__ olog,
                             float* __restrict__ w_a,
                             float* __restrict__ w_o) {
    int b = blockIdx.x >> 1;
    int which = blockIdx.x & 1;
    const float* lg = which ? olog : alog;
    float* wout = which ? w_o : w_a;
    __shared__ float raw[SS * CC];   // 40 KB
    __shared__ float sl[SS];         // 8 KB
    __shared__ float red[256];
    int t = threadIdx.x;
    const float4* src = (const float4*)(lg + (size_t)b * SS * CC);
    float4* dst = (float4*)raw;
    #pragma unroll 4
    for (int i = t; i < SS * CC / 4; i += 256) dst[i] = src[i];
    __syncthreads();
    for (int s = t; s < SS; s += 256) {
        int base = s * 5;
        sl[s] = raw[base + 1] + raw[base + 2] + raw[base + 3] + raw[base + 4];
    }
    __syncthreads();
    float m = -1e30f;
    for (int s = t; s < SS; s += 256) m = fmaxf(m, sl[s]);
    red[t] = m;
    __syncthreads();
    for (int o = 128; o > 0; o >>= 1) {
        if (t < o) red[t] = fmaxf(red[t], red[t + o]);
        __syncthreads();
    }
    m = red[0];
    __syncthreads();
    float sum = 0.f;
    for (int s = t; s < SS; s += 256) {
        float e = expf(sl[s] - m);
        sl[s] = e;
        sum += e;
    }
    red[t] = sum;
    __syncthreads();
    for (int o = 128; o > 0; o >>= 1) {
        if (t < o) red[t] += red[t + o];
        __syncthreads();
    }
    float inv = 1.0f / red[0];
    for (int s = t; s < SS; s += 256) wout[(size_t)b * SS + s] = sl[s] * inv;
}

// ---------------------------------------------------------------------------
// K2: pooling main pass — part[chunk][b][h] = sum over 64 s of span*w
// grid: 1024 = b(32) x chunk(32), block: 256 threads, 4 h each (float4)
// 268 MB streaming kernel; unroll 16 -> 16 float4 loads in flight per thread.
__global__ __launch_bounds__(256) void pool_partial(const float* __restrict__ span,
                             const float* __restrict__ w_a,
                             const float* __restrict__ w_o,
                             float* __restrict__ part_a,
                             float* __restrict__ part_o) {
    int b = blockIdx.x >> 5;
    int chunk = blockIdx.x & 31;
    int t = threadIdx.x;
    __shared__ float wa[64], wo[64];
    int s0 = chunk * 64;
    if (t < 64) {
        wa[t] = w_a[(size_t)b * SS + s0 + t];
        wo[t] = w_o[(size_t)b * SS + s0 + t];
    }
    __syncthreads();
    const float4* sp = (const float4*)span + ((size_t)b * SS + s0) * (HH / 4) + t;
    float4 aa = {0.f, 0.f, 0.f, 0.f};
    float4 oo = {0.f, 0.f, 0.f, 0.f};
    #pragma unroll 16
    for (int ss = 0; ss < 64; ++ss) {
        float4 v = sp[(size_t)ss * (HH / 4)];
        float fa = wa[ss], fo = wo[ss];
        aa.x += v.x * fa; aa.y += v.y * fa; aa.z += v.z * fa; aa.w += v.w * fa;
        oo.x += v.x * fo; oo.y += v.y * fo; oo.z += v.z * fo; oo.w += v.w * fo;
    }
    size_t idx = ((size_t)chunk * BB + b) * HH + (size_t)t * 4;
    *(float4*)(part_a + idx) = aa;
    *(float4*)(part_o + idx) = oo;
}

// K2r: reduce 32 partials -> a_emb/o_emb [32][1024]
__global__ __launch_bounds__(256) void pool_reduce(const float* __restrict__ part_a,
                            const float* __restrict__ part_o,
                            float* __restrict__ a_emb,
                            float* __restrict__ o_emb) {
    int gid = blockIdx.x * 256 + threadIdx.x;
    int which = gid >> 15;
    int r = gid & 32767;
    const float* p = which ? part_o : part_a;
    float s = 0.f;
    #pragma unroll
    for (int c = 0; c < 32; ++c) s += p[(size_t)c * 32768 + r];
    (which ? o_emb : a_emb)[r] = s;
}

// ---------------------------------------------------------------------------
// K3: all three layer-1 GEMMs in one launch, W streamed once, k-split partials.
// grid: 384 blocks: [0,64)=a (8j x 8k), [64,128)=o, [128,384)=s (16j x 16k).
// block 512 = 64 j-lanes x 8 b-groups (4 batch rows each).
// unroll 8 on the k+=4 loop -> 32 scalar W loads in flight.
__global__ __launch_bounds__(512) void gemm1_all(const float* __restrict__ a_emb, const float* __restrict__ o_emb,
                          const float* __restrict__ Wa1, const float* __restrict__ Wo1,
                          const float* __restrict__ Ws1,
                          float* __restrict__ p1_a, float* __restrict__ p1_o,
                          float* __restrict__ p1_s) {
    int bid = blockIdx.x;
    const float* xp; const float* W; float* part; int N, kb, jb;
    if (bid < 64) {
        jb = bid & 7; kb = bid >> 3; N = 512; W = Wa1; part = p1_a;
        xp = a_emb + kb * 128;
    } else if (bid < 128) {
        int r = bid - 64;
        jb = r & 7; kb = r >> 3; N = 512; W = Wo1; part = p1_o;
        xp = o_emb + kb * 128;
    } else {
        int r = bid - 128;
        jb = r & 15; kb = r >> 4; N = 1024; W = Ws1; part = p1_s;
        int kk0 = kb * 128;   // chunks never straddle the 1024 boundary
        xp = (kk0 < 1024) ? (a_emb + kk0) : (o_emb + (kk0 - 1024));
    }
    int k0 = kb * 128;   // global k row offset into W
    __shared__ float xs[32][128];   // 16 KB
    int t = threadIdx.x;
    #pragma unroll
    for (int i = 0; i < 2; ++i) {
        int f = t + i * 512;        // float4 index into [32][32]
        int b = f >> 5;
        int kk = (f & 31) * 4;
        *(float4*)(&xs[b][kk]) = *(const float4*)(xp + (size_t)b * HH + kk);
    }
    __syncthreads();
    int jl = t & 63, bg = t >> 6;   // bg 0..7
    int j = jb * 64 + jl;
    float acc[4] = {0.f, 0.f, 0.f, 0.f};
    const float* Wp = W + (size_t)k0 * N + j;
    #pragma unroll 8
    for (int k = 0; k < 128; k += 4) {
        float w0 = Wp[(size_t)(k + 0) * N];
        float w1 = Wp[(size_t)(k + 1) * N];
        float w2 = Wp[(size_t)(k + 2) * N];
        float w3 = Wp[(size_t)(k + 3) * N];
        #pragma unroll
        for (int bi = 0; bi < 4; ++bi) {
            float4 xv = *(const float4*)(&xs[bg * 4 + bi][k]);
            acc[bi] += xv.x * w0 + xv.y * w1 + xv.z * w2 + xv.w * w3;
        }
    }
    float* pp = part + (size_t)kb * 32 * N + j;
    #pragma unroll
    for (int bi = 0; bi < 4; ++bi)
        pp[(size_t)(bg * 4 + bi) * N] = acc[bi];
}

// ---------------------------------------------------------------------------
// K4: layer 2 for a/o/s, fused k-split reduction + bias + relu of layer1.
// GEMV k-loops unrolled 16 (16 independent W2 loads in flight).
// grid: 96 blocks: [0,32)=a, [32,64)=o, [64,96)=s. block: 512.
__global__ __launch_bounds__(512) void layer2_all(const float* __restrict__ p1_a, const float* __restrict__ ba1,
                           const float* __restrict__ Wa2, const float* __restrict__ ba2,
                           const float* __restrict__ p1_o, const float* __restrict__ bo1,
                           const float* __restrict__ Wo2, const float* __restrict__ bo2,
                           const float* __restrict__ p1_s, const float* __restrict__ bs1,
                           const float* __restrict__ Ws2, const float* __restrict__ bs2,
                           float* __restrict__ a_proj, float* __restrict__ o_proj,
                           float* __restrict__ s_proj) {
    __shared__ float x[1024];
    __shared__ float red[512];
    int bid = blockIdx.x;
    int t = threadIdx.x;
    if (bid < 64) {
        int which = bid >> 5;
        int b = bid & 31;
        const float* part = which ? p1_o : p1_a;
        const float* b1 = which ? bo1 : ba1;
        const float* W2 = which ? Wo2 : Wa2;
        const float* b2 = which ? bo2 : ba2;
        float* out = (which ? o_proj : a_proj) + (size_t)b * 128;
        {   // reduce 8 k-split partials + bias + relu  (t = j, one per thread)
            float s = b1[t];
            #pragma unroll
            for (int kb = 0; kb < 8; ++kb) s += part[(size_t)kb * 32 * 512 + (size_t)b * 512 + t];
            x[t] = fmaxf(s, 0.f);
        }
        __syncthreads();
        int jj = t & 127, kh = t >> 7;     // 4-way k split
        int kbase = kh * 128;
        const float* Wc = W2 + (size_t)kbase * 128 + jj;
        float acc = 0.f;
        #pragma unroll 16
        for (int kk = 0; kk < 128; ++kk)
            acc += x[kbase + kk] * Wc[(size_t)kk * 128];
        if (kh == 0) acc += b2[jj];
        red[t] = acc;
        __syncthreads();
        float tot = 0.f;
        if (t < 128) tot = red[t] + red[t + 128] + red[t + 256] + red[t + 384];
        __syncthreads();
        if (t < 128) red[t] = tot * tot;
        __syncthreads();
        for (int o = 64; o > 0; o >>= 1) {
            if (t < o) red[t] += red[t + o];
            __syncthreads();
        }
        float n = fmaxf(sqrtf(red[0]), 1e-12f);
        if (t < 128) out[t] = tot / n;
    } else {
        int b = bid - 64;
        for (int j = t; j < 1024; j += 512) {
            float s = bs1[j];
            #pragma unroll
            for (int kb = 0; kb < 16; ++kb) s += p1_s[(size_t)kb * 32 * 1024 + (size_t)b * 1024 + j];
            x[j] = fmaxf(s, 0.f);
        }
        __syncthreads();
        int jj = t & 255, kh = t >> 8;     // 2-way k split
        int kbase = kh * 512;
        const float* Wc = Ws2 + (size_t)kbase * 256 + jj;
        float acc = 0.f;
        #pragma unroll 16
        for (int kk = 0; kk < 512; ++kk)
            acc += x[kbase + kk] * Wc[(size_t)kk * 256];
        if (kh == 0) acc += bs2[jj];
        red[t] = acc;
        __syncthreads();
        float tot = 0.f;
        if (t < 256) tot = red[t] + red[t + 256];
        __syncthreads();
        if (t < 256) red[t] = tot * tot;
        __syncthreads();
        for (int o = 128; o > 0; o >>= 1) {
            if (t < o) red[t] += red[t + o];
            __syncthreads();
        }
        float n = fmaxf(sqrtf(red[0]), 1e-12f);
        if (t < 256) s_proj[(size_t)b * 256 + t] = tot / n;
    }
}

// ---------------------------------------------------------------------------
// K5: loss rows. ROUND-3 FIX: the old single-block kernel put 16 waves and
// ~768 scalar ds_read per thread on ONE CU's LDS pipe (~15us). Now 32 blocks
// (one per sim row i), 8 threads per dot with shfl-group reduction, float4
// LDS reads with interleaved granules (conflict-free: col = (q*8+l)*4).
// Writes per-row results to rowbuf[0..31]=rowv, [32..63]=rownt, [64..95]=has.
__global__ __launch_bounds__(256) void loss_rows(const float* __restrict__ a_proj,
                            const float* __restrict__ o_proj,
                            const float* __restrict__ s_proj,
                            const int* __restrict__ labels,
                            float* __restrict__ rowbuf) {
    int i = blockIdx.x;
    __shared__ __align__(16) float spn[BB][260];   // 256 + 4 pad (16B-odd stride)
    __shared__ __align__(16) float opn[BB][132];   // 128 + 4 pad
    __shared__ __align__(16) float api[128];
    __shared__ float invn[BB];
    __shared__ float jv[BB][5];
    __shared__ int lab[BB];
    int t = threadIdx.x;
    // stage: sp 2048 f4, op 1024 f4, a row i 32 f4 — all coalesced
    for (int q = t; q < 2048; q += 256) {
        int r = q >> 6, c = (q & 63) << 2;
        *(float4*)&spn[r][c] = *(const float4*)(s_proj + r * 256 + c);
    }
    for (int q = t; q < 1024; q += 256) {
        int r = q >> 5, c = (q & 31) << 2;
        *(float4*)&opn[r][c] = *(const float4*)(o_proj + r * 128 + c);
    }
    if (t < 32) *(float4*)&api[t * 4] = *(const float4*)(a_proj + (size_t)i * 128 + t * 4);
    if (t < BB) lab[t] = labels[t];
    __syncthreads();

    int r = t >> 3, l = t & 7;   // 32 groups of 8 lanes
    // row norms of sp (reference re-normalizes inside _ntxent)
    {
        float ssq = 0.f;
        #pragma unroll
        for (int q = 0; q < 8; ++q) {
            int c = (q * 8 + l) * 4;
            float4 v = *(float4*)&spn[r][c];
            ssq += v.x * v.x + v.y * v.y + v.z * v.z + v.w * v.w;
        }
        ssq += __shfl_xor(ssq, 1, 8);
        ssq += __shfl_xor(ssq, 2, 8);
        ssq += __shfl_xor(ssq, 4, 8);
        if (l == 0) invn[r] = 1.0f / fmaxf(sqrtf(ssq), 1e-12f);
    }
    __syncthreads();
    {   // normalize in place
        float s = invn[r];
        #pragma unroll
        for (int q = 0; q < 8; ++q) {
            int c = (q * 8 + l) * 4;
            float4 v = *(float4*)&spn[r][c];
            v.x *= s; v.y *= s; v.z *= s; v.w *= s;
            *(float4*)&spn[r][c] = v;
        }
    }
    __syncthreads();

    int j = r;   // group index = column j of the sim row
    // infonce dot: a_proj[i] . o_proj[j], 128 elems, 16 per lane
    float dot = 0.f;
    #pragma unroll
    for (int q = 0; q < 4; ++q) {
        int c = (q * 8 + l) * 4;
        float4 av = *(float4*)&api[c];
        float4 ov = *(float4*)&opn[j][c];
        dot += av.x * ov.x + av.y * ov.y + av.z * ov.z + av.w * ov.w;
    }
    // ntxent dot: spn[i] . spn[j], 256 elems, 32 per lane
    float dn = 0.f;
    #pragma unroll
    for (int q = 0; q < 8; ++q) {
        int c = (q * 8 + l) * 4;
        float4 si = *(float4*)&spn[i][c];
        float4 sj = *(float4*)&spn[j][c];
        dn += si.x * sj.x + si.y * sj.y + si.z * sj.z + si.w * sj.w;
    }
    dot += __shfl_xor(dot, 1, 8); dot += __shfl_xor(dot, 2, 8); dot += __shfl_xor(dot, 4, 8);
    dn  += __shfl_xor(dn, 1, 8);  dn  += __shfl_xor(dn, 2, 8);  dn  += __shfl_xor(dn, 4, 8);
    if (l == 0) {
        float e = expf(dot * TEMP_INV);
        float maskv = (i == j) ? 1.0f : ((lab[i] == lab[j]) ? 0.5f : 0.0f);
        float en = expf(dn * TEMP_INV);
        float mnt = (lab[i] == lab[j]) ? ((i == j) ? 0.f : 1.f) : 0.f;
        jv[j][0] = e * maskv;
        jv[j][1] = e;
        jv[j][2] = en * mnt;
        jv[j][3] = en * (1.f - mnt);
        jv[j][4] = mnt;
    }
    __syncthreads();
    if (t < 32) {
        float num = jv[t][0], den = jv[t][1], pos = jv[t][2], neg = jv[t][3], pc = jv[t][4];
        for (int m = 16; m > 0; m >>= 1) {
            num += __shfl_xor(num, m, 32);
            den += __shfl_xor(den, m, 32);
            pos += __shfl_xor(pos, m, 32);
            neg += __shfl_xor(neg, m, 32);
            pc  += __shfl_xor(pc, m, 32);
        }
        if (t == 0) {
            rowbuf[i] = -logf(num / den + 1e-8f);
            bool has = pc > 0.f;
            rowbuf[32 + i] = has ? (-logf(pos / (pos + neg) + 1e-8f) / fmaxf(pc, 1.0f)) : 0.f;
            rowbuf[64 + i] = has ? 1.f : 0.f;
        }
    }
}

// K6: deterministic final combine (fixed order, matches old t==0 loop).
__global__ __launch_bounds__(64) void loss_final(const float* __restrict__ rowbuf,
                                                 float* __restrict__ out) {
    if (threadIdx.x == 0) {
        float inf = 0.f, nt = 0.f;
        int h = 0;
        #pragma unroll
        for (int q = 0; q < 32; ++q) {
            inf += rowbuf[q];
            nt += rowbuf[32 + q];
            h += (rowbuf[64 + q] > 0.5f) ? 1 : 0;
        }
        inf /= (float)BB;
        nt /= (float)(h > 0 ? h : 1);
        out[0] = 1.0f * inf + 0.5f * nt;
    }
}

// ---------------------------------------------------------------------------
extern "C" void kernel_launch(void* const* d_in, const int* in_sizes, int n_in,
                              void* d_out, int out_size, void* d_ws, size_t ws_size,
                              hipStream_t stream) {
    const float* span  = (const float*)d_in[0];
    const float* alog  = (const float*)d_in[1];
    const float* olog  = (const float*)d_in[2];
    const int*   labs  = (const int*)d_in[3];
    const float* Wa1   = (const float*)d_in[4];
    const float* ba1   = (const float*)d_in[5];
    const float* Wa2   = (const float*)d_in[6];
    const float* ba2   = (const float*)d_in[7];
    const float* Wo1   = (const float*)d_in[8];
    const float* bo1   = (const float*)d_in[9];
    const float* Wo2   = (const float*)d_in[10];
    const float* bo2   = (const float*)d_in[11];
    const float* Ws1   = (const float*)d_in[12];
    const float* bs1   = (const float*)d_in[13];
    const float* Ws2   = (const float*)d_in[14];
    const float* bs2   = (const float*)d_in[15];

    float* ws = (float*)d_ws;
    float* w_a    = ws;                  // 65536
    float* w_o    = ws + 65536;          // 65536
    float* part_a = ws + 131072;         // 32*32768 = 1048576
    float* part_o = ws + 1179648;        // 1048576
    float* a_emb  = ws + 2228224;        // 32768
    float* o_emb  = ws + 2260992;        // 32768
    float* p1_a   = ws + 2293760;        // 8*32*512 = 131072
    float* p1_o   = ws + 2424832;        // 131072
    float* p1_s   = ws + 2555904;        // 16*32*1024 = 524288
    float* a_proj = ws + 3080192;        // 4096
    float* o_proj = ws + 3084288;        // 4096
    float* s_proj = ws + 3088384;        // 8192
    float* rowbuf = ws + 3096576;        // 96

    hipLaunchKernelGGL(pool_weights, dim3(64), dim3(256), 0, stream, alog, olog, w_a, w_o);
    hipLaunchKernelGGL(pool_partial, dim3(1024), dim3(256), 0, stream,
                       span, w_a, w_o, part_a, part_o);
    hipLaunchKernelGGL(pool_reduce, dim3(256), dim3(256), 0, stream,
                       part_a, part_o, a_emb, o_emb);
    hipLaunchKernelGGL(gemm1_all, dim3(384), dim3(512), 0, stream,
                       a_emb, o_emb, Wa1, Wo1, Ws1, p1_a, p1_o, p1_s);
    hipLaunchKernelGGL(layer2_all, dim3(96), dim3(512), 0, stream,
                       p1_a, ba1, Wa2, ba2, p1_o, bo1, Wo2, bo2,
                       p1_s, bs1, Ws2, bs2, a_proj, o_proj, s_proj);
    hipLaunchKernelGGL(loss_rows, dim3(32), dim3(256), 0, stream,
                       a_proj, o_proj, s_proj, labs, rowbuf);
    hipLaunchKernelGGL(loss_final, dim3(1), dim3(64), 0, stream,
                       rowbuf, (float*)d_out);
}